// Round 1
// 12989.320 us; speedup vs baseline: 1.1671x; 1.1671x over previous
//
#include <hip/hip_runtime.h>
#include <hip/hip_bf16.h>

// Problem constants (match reference)
constexpr int Bc   = 2;
constexpr int Tc   = 1024;
constexpr int Vc   = 50257;
constexpr int Lc   = 8;
constexpr int Dc   = 1024;
constexpr int Hc   = 16;
constexpr int HKVc = 4;
constexpr int HDc  = 64;     // D/H
constexpr int KVDc = 256;    // HKV*HD
constexpr int MLPc = 4096;   // 4*D
constexpr int BVc  = 65536;
constexpr int BDc  = 256;
constexpr int VEDc = 128;

constexpr int NTOK = Bc * Tc;          // 2048
constexpr long SZ_X  = (long)NTOK * Dc;    // 2,097,152
constexpr long SZ_KV = (long)NTOK * KVDc;  // 524,288
constexpr long SZ_H  = (long)NTOK * MLPc;  // 8,388,608

#define NEG_BIG (-3.0e38f)

typedef __attribute__((ext_vector_type(8))) short short8;   // 8 bf16 (4 VGPRs)
typedef __attribute__((ext_vector_type(4))) float floatx4;  // MFMA acc

__device__ __forceinline__ float wave_sum(float v) {
#pragma unroll
  for (int off = 32; off >= 1; off >>= 1) v += __shfl_xor(v, off);
  return v;
}
__device__ __forceinline__ float wave_max(float v) {
#pragma unroll
  for (int off = 32; off >= 1; off >>= 1) v = fmaxf(v, __shfl_xor(v, off));
  return v;
}

// ---------------------------------------------------------------------------
// Embedding: raw_x = rms(embed_w[id]) + big_w[bg] @ big_proj.T * big_scale
//            vemb  = ve_w[id] @ ve_proj.T * ve_scale
// One block (256 threads) per token.
// ---------------------------------------------------------------------------
__global__ __launch_bounds__(256) void embed_kernel(
    const int* __restrict__ ids, const float* __restrict__ embed_w,
    const float* __restrict__ big_w, const float* __restrict__ big_proj,
    const float* __restrict__ big_scale, const float* __restrict__ ve_w,
    const float* __restrict__ ve_proj, const float* __restrict__ ve_scale,
    float* __restrict__ raw_x, float* __restrict__ vemb) {
  int bt = blockIdx.x;
  int tid = threadIdx.x;
  int t = bt % Tc;
  int tok = ids[bt];

  const float* e = embed_w + (size_t)tok * Dc;
  float ev[4];
  float ss = 0.f;
#pragma unroll
  for (int i = 0; i < 4; ++i) {
    ev[i] = e[tid + i * 256];
    ss += ev[i] * ev[i];
  }
  __shared__ float red[4];
  __shared__ float brow[BDc];
  __shared__ float verow[VEDc];
  float wsum = wave_sum(ss);
  if ((tid & 63) == 0) red[tid >> 6] = wsum;

  // bigram hash index
  int bg;
  if (t == 0) {
    bg = BVc - 1;
  } else {
    unsigned a = (unsigned)ids[bt];
    unsigned p = (unsigned)ids[bt - 1];
    bg = (int)(((36313u * a) ^ (27191u * p)) % 65535u);
  }
  brow[tid] = big_w[(size_t)bg * BDc + tid];
  if (tid < VEDc) verow[tid] = ve_w[(size_t)tok * VEDc + tid];
  __syncthreads();

  float tot = red[0] + red[1] + red[2] + red[3];
  float rn = rsqrtf(tot / (float)Dc + 1e-6f);
  float bs = big_scale[0];
#pragma unroll
  for (int i = 0; i < 4; ++i) {
    int d = tid + i * 256;
    const float* bp = big_proj + (size_t)d * BDc;
    float dot = 0.f;
    for (int c = 0; c < BDc; ++c) dot += brow[c] * bp[c];
    raw_x[(size_t)bt * Dc + d] = ev[i] * rn + dot * bs;
  }
  {
    float vs = ve_scale[0];
    int d = tid;  // 0..255
    const float* vp = ve_proj + (size_t)d * VEDc;
    float dot = 0.f;
    for (int c = 0; c < VEDc; ++c) dot += verow[c] * vp[c];
    vemb[(size_t)bt * KVDc + d] = dot * vs;
  }
}

// ---------------------------------------------------------------------------
// Smear: x = (1-g)*raw + g*raw_prev_token ; x0 = x
// ---------------------------------------------------------------------------
__global__ __launch_bounds__(256) void smear_kernel(
    const float* __restrict__ raw, const float* __restrict__ gate,
    float* __restrict__ x, float* __restrict__ x0) {
  long idx = (long)blockIdx.x * 256 + threadIdx.x;
  if (idx >= SZ_X) return;
  int d = (int)(idx & (Dc - 1));
  int t = (int)((idx / Dc) & (Tc - 1));
  float g = 1.f / (1.f + expf(-gate[d]));
  float cur = raw[idx];
  float prev = (t > 0) ? raw[idx - Dc] : 0.f;
  float val = (1.f - g) * cur + g * prev;
  x[idx] = val;
  x0[idx] = val;
}

// ---------------------------------------------------------------------------
// Pre-layer: x_in = mix0*x + mix1*x0 ; xn = rms(x_in). Block per token.
// ---------------------------------------------------------------------------
__global__ __launch_bounds__(256) void prelayer_kernel(
    const float* __restrict__ x, const float* __restrict__ x0,
    const float* __restrict__ mix, float* __restrict__ x_in,
    float* __restrict__ xn) {
  int bt = blockIdx.x;
  int tid = threadIdx.x;
  const float* xr = x + (size_t)bt * Dc;
  const float* x0r = x0 + (size_t)bt * Dc;
  float vals[4];
  float ss = 0.f;
#pragma unroll
  for (int i = 0; i < 4; ++i) {
    int d = tid + i * 256;
    float v = mix[d] * xr[d] + mix[Dc + d] * x0r[d];
    vals[i] = v;
    ss += v * v;
  }
  __shared__ float red[4];
  float wsum = wave_sum(ss);
  if ((tid & 63) == 0) red[tid >> 6] = wsum;
  __syncthreads();
  float tot = red[0] + red[1] + red[2] + red[3];
  float rn = rsqrtf(tot / (float)Dc + 1e-6f);
#pragma unroll
  for (int i = 0; i < 4; ++i) {
    int d = tid + i * 256;
    x_in[(size_t)bt * Dc + d] = vals[i];
    xn[(size_t)bt * Dc + d] = vals[i] * rn;
  }
}

// ---------------------------------------------------------------------------
// Plain RMS over D. Block per token.
// ---------------------------------------------------------------------------
__global__ __launch_bounds__(256) void rms_kernel(const float* __restrict__ in,
                                                  float* __restrict__ out) {
  int bt = blockIdx.x;
  int tid = threadIdx.x;
  const float* p = in + (size_t)bt * Dc;
  float v[4];
  float ss = 0.f;
#pragma unroll
  for (int i = 0; i < 4; ++i) {
    v[i] = p[tid + i * 256];
    ss += v[i] * v[i];
  }
  __shared__ float red[4];
  float wsum = wave_sum(ss);
  if ((tid & 63) == 0) red[tid >> 6] = wsum;
  __syncthreads();
  float tot = red[0] + red[1] + red[2] + red[3];
  float rn = rsqrtf(tot / (float)Dc + 1e-6f);
  float* o = out + (size_t)bt * Dc;
#pragma unroll
  for (int i = 0; i < 4; ++i) o[tid + i * 256] = v[i] * rn;
}

// ---------------------------------------------------------------------------
// bf16 split helpers: f = bf2f(hi) + bf2f(lo) + O(2^-17 * f)
// ---------------------------------------------------------------------------
__device__ __forceinline__ short f2bf(float f) {
  unsigned u = __float_as_uint(f);
  return (short)((u + 0x7fffu + ((u >> 16) & 1u)) >> 16);
}
__device__ __forceinline__ float bf2f(short h) {
  return __uint_as_float(((unsigned)(unsigned short)h) << 16);
}
__device__ __forceinline__ void cvt_store(short* hp, short* lp, float4 f0,
                                          float4 f1) {
  float fv[8] = {f0.x, f0.y, f0.z, f0.w, f1.x, f1.y, f1.z, f1.w};
  short8 hi, lo;
#pragma unroll
  for (int i = 0; i < 8; ++i) {
    short h = f2bf(fv[i]);
    hi[i] = h;
    lo[i] = f2bf(fv[i] - bf2f(h));
  }
  *(short8*)hp = hi;
  *(short8*)lp = lo;
}

// ---------------------------------------------------------------------------
// MFMA GEMM (bf16x2 split, fp32-accurate): C[M,N] = epi( A[M,K] @ W[N,K].T )
//   epi: act==1 -> leaky(0.5) then square; then *colscale[n]; then +base[m,n]
// 128x128 tile, BK=32, 256 threads = 4 waves (2x2), each wave 64x64 via
// 4x4 frags of v_mfma_f32_16x16x32_bf16. hi*hi + hi*lo + lo*hi accumulation.
// LDS layout per 16-row x 32-k subtile is MFMA-lane order: lane l holds
// row (l&15), k-octet (l>>4) at byte offset l*16 -> contiguous 1024B per
// subtile => conflict-free ds_read_b128 / ds_write_b128.
// Requires K % 32 == 0, M % 128 == 0. N arbitrary.
// grid = (M/128, ceil(N/128)): M inner so concurrent blocks share W tiles.
// ---------------------------------------------------------------------------
__global__ __launch_bounds__(256) void gemm_mfma(
    const float* __restrict__ A, const float* __restrict__ W,
    float* __restrict__ C, const float* __restrict__ base,
    const float* __restrict__ colscale, int M, int N, int K, int act) {
  __shared__ short lds[16384];  // 32 KiB: A_hi, A_lo, B_hi, B_lo (4096 each)
  short* As_hi = lds;
  short* As_lo = lds + 4096;
  short* Bs_hi = lds + 8192;
  short* Bs_lo = lds + 12288;
  int tid = threadIdx.x;
  int lane = tid & 63, wv = tid >> 6;
  int wm = (wv >> 1) * 64, wn = (wv & 1) * 64;
  int m0 = blockIdx.x * 128, n0 = blockIdx.y * 128;

  floatx4 acc[4][4] = {};

  for (int k0 = 0; k0 < K; k0 += 32) {
    // ---- stage: 128x32 fp32 of A and of W -> hi/lo bf16 planes in LDS
#pragma unroll
    for (int cc = 0; cc < 2; ++cc) {
      int c = tid + cc * 256;    // chunk 0..511
      int r = c >> 2;            // tile row 0..127
      int kg = c & 3;            // k-octet 0..3
      int off = (r >> 4) * 512 + ((r & 15) + kg * 16) * 8;  // shorts
      {
        const float* src = A + (size_t)(m0 + r) * K + k0 + kg * 8;
        float4 f0 = *(const float4*)src;
        float4 f1 = *(const float4*)(src + 4);
        cvt_store(As_hi + off, As_lo + off, f0, f1);
      }
      {
        int gn = n0 + r;
        float4 f0 = make_float4(0.f, 0.f, 0.f, 0.f), f1 = f0;
        if (gn < N) {
          const float* src = W + (size_t)gn * K + k0 + kg * 8;
          f0 = *(const float4*)src;
          f1 = *(const float4*)(src + 4);
        }
        cvt_store(Bs_hi + off, Bs_lo + off, f0, f1);
      }
    }
    __syncthreads();
    // ---- fragments + MFMA
    short8 ah[4], al[4], bh[4], bl[4];
    int ab = wm >> 4, bb = wn >> 4;
#pragma unroll
    for (int i = 0; i < 4; ++i) {
      int offa = (ab + i) * 512 + lane * 8;
      ah[i] = *(const short8*)(As_hi + offa);
      al[i] = *(const short8*)(As_lo + offa);
      int offb = (bb + i) * 512 + lane * 8;
      bh[i] = *(const short8*)(Bs_hi + offb);
      bl[i] = *(const short8*)(Bs_lo + offb);
    }
#pragma unroll
    for (int i = 0; i < 4; ++i)
#pragma unroll
      for (int j = 0; j < 4; ++j) {
        acc[i][j] =
            __builtin_amdgcn_mfma_f32_16x16x32_bf16(ah[i], bh[j], acc[i][j], 0, 0, 0);
        acc[i][j] =
            __builtin_amdgcn_mfma_f32_16x16x32_bf16(ah[i], bl[j], acc[i][j], 0, 0, 0);
        acc[i][j] =
            __builtin_amdgcn_mfma_f32_16x16x32_bf16(al[i], bh[j], acc[i][j], 0, 0, 0);
      }
    __syncthreads();
  }
  // ---- epilogue: C/D layout col=lane&15, row=(lane>>4)*4+reg
#pragma unroll
  for (int i = 0; i < 4; ++i) {
#pragma unroll
    for (int j = 0; j < 4; ++j) {
      int col = n0 + wn + 16 * j + (lane & 15);
      if (col >= N) continue;
      int row0 = m0 + wm + 16 * i + (lane >> 4) * 4;
      floatx4 f = acc[i][j];
#pragma unroll
      for (int r = 0; r < 4; ++r) {
        float v = f[r];
        if (act == 1) {
          float h = (v >= 0.f) ? v : 0.5f * v;
          v = h * h;
        }
        if (colscale) v *= colscale[col];
        size_t idx = (size_t)(row0 + r) * N + col;
        if (base) v += base[idx];
        C[idx] = v;
      }
    }
  }
}

// ---------------------------------------------------------------------------
// QK head-RMS + RoPE (+q_gain). Block per token; wave w handles q heads
// {w, w+4, w+8, w+12} and kv head w. lane = dim within head.
// ---------------------------------------------------------------------------
__global__ __launch_bounds__(256) void qkrope_kernel(
    float* __restrict__ q, float* __restrict__ k,
    const float* __restrict__ q_gain) {
  int bt = blockIdx.x;
  int t = bt % Tc;
  int tid = threadIdx.x;
  int lane = tid & 63, wv = tid >> 6;
  int fi = lane & 31;
  // inv = 10000^(-2*fi/64); angle = t * inv
  float inv = expf(-(float)(2 * fi) * (9.210340372f / 64.f));
  float ang = (float)t * inv;
  float cv = cosf(ang);
  float sv = sinf(ang);

#pragma unroll
  for (int hh = 0; hh < 4; ++hh) {
    int h = wv + hh * 4;
    float* qp = q + (size_t)bt * Dc + h * 64;
    float val = qp[lane];
    float ss = wave_sum(val * val);
    float rn = rsqrtf(ss / 64.f + 1e-6f);
    val *= rn;
    float partner = __shfl(val, lane ^ 32);
    float out = (lane < 32) ? (val * cv + partner * sv) : (val * cv - partner * sv);
    out *= q_gain[h];
    qp[lane] = out;
  }
  {
    int h = wv;  // 4 waves == HKV heads
    float* kp = k + (size_t)bt * KVDc + h * 64;
    float val = kp[lane];
    float ss = wave_sum(val * val);
    float rn = rsqrtf(ss / 64.f + 1e-6f);
    val *= rn;
    float partner = __shfl(val, lane ^ 32);
    float out = (lane < 32) ? (val * cv + partner * sv) : (val * cv - partner * sv);
    kp[lane] = out;
  }
}

// ---------------------------------------------------------------------------
// Causal GQA attention + v-direction-removal epilogue.
// Grid: (T, B*HKV). Block 256 = 4 waves = the G=4 query heads of this kv head.
// Wave-per-query-row flash: lane==key within tile for scores; lane==dim for PV.
// ---------------------------------------------------------------------------
__global__ __launch_bounds__(256) void attn_kernel(
    const float* __restrict__ q, const float* __restrict__ k,
    const float* __restrict__ v, float* __restrict__ y) {
  __shared__ float kt[64][65];
  __shared__ float vt[64][65];
  int qpos = blockIdx.x;
  int bh = blockIdx.y;
  int b = bh / HKVc, hkv = bh % HKVc;
  int tid = threadIdx.x;
  int lane = tid & 63, wv = tid >> 6;
  int h = hkv * 4 + wv;

  float qv = q[((size_t)(b * Tc + qpos)) * Dc + h * 64 + lane];
  float m_run = NEG_BIG, l_run = 0.f, o = 0.f;
  int ntiles = qpos / 64 + 1;
  for (int jt = 0; jt < ntiles; ++jt) {
    // stage 64 keys + 64 values (64x64 each)
#pragma unroll
    for (int i = 0; i < 4; ++i) {
      int idx = tid + i * 256;      // 0..1023 float4 slots
      int rr = idx >> 4;            // row 0..63
      int cc = idx & 15;            // float4 col 0..15
      size_t off = ((size_t)(b * Tc + jt * 64 + rr)) * KVDc + hkv * 64 + cc * 4;
      float4 k4 = *(const float4*)(k + off);
      float4 v4 = *(const float4*)(v + off);
      kt[rr][cc * 4 + 0] = k4.x; kt[rr][cc * 4 + 1] = k4.y;
      kt[rr][cc * 4 + 2] = k4.z; kt[rr][cc * 4 + 3] = k4.w;
      vt[rr][cc * 4 + 0] = v4.x; vt[rr][cc * 4 + 1] = v4.y;
      vt[rr][cc * 4 + 2] = v4.z; vt[rr][cc * 4 + 3] = v4.w;
    }
    __syncthreads();
    // scores: lane = key index in tile
    float s = 0.f;
#pragma unroll 8
    for (int d = 0; d < 64; ++d) {
      float qd = __shfl(qv, d);
      s += kt[lane][d] * qd;
    }
    s *= 0.125f;  // 1/sqrt(64)
    int jg = jt * 64 + lane;
    if (jg > qpos) s = NEG_BIG;
    float mt = wave_max(s);
    float m_new = fmaxf(m_run, mt);
    float alpha = expf(m_run - m_new);
    float p = expf(s - m_new);
    float psum = wave_sum(p);
    l_run = l_run * alpha + psum;
    m_run = m_new;
    o *= alpha;
    // PV: lane = dim
#pragma unroll 8
    for (int j = 0; j < 64; ++j) {
      float pj = __shfl(p, j);
      o += pj * vt[j][lane];
    }
    __syncthreads();
  }
  o /= l_run;
  // remove component along normalized v at query position
  float vv = v[((size_t)(b * Tc + qpos)) * KVDc + hkv * 64 + lane];
  float n2 = wave_sum(vv * vv);
  float nrm = sqrtf(n2);
  float vn = vv / fmaxf(nrm, 1e-12f);
  float dt = wave_sum(o * vn);
  float yo = o - dt * vn;
  y[((size_t)(b * Tc + qpos)) * Dc + h * 64 + lane] = yo;
}

// ---------------------------------------------------------------------------
extern "C" void kernel_launch(void* const* d_in, const int* in_sizes, int n_in,
                              void* d_out, int out_size, void* d_ws,
                              size_t ws_size, hipStream_t stream) {
  const int* ids          = (const int*)d_in[0];
  const float* embed_w    = (const float*)d_in[1];
  const float* big_w      = (const float*)d_in[2];
  const float* big_proj   = (const float*)d_in[3];
  const float* big_scale  = (const float*)d_in[4];
  const float* smear_gate = (const float*)d_in[5];
  const float* ve_w       = (const float*)d_in[6];
  const float* ve_proj    = (const float*)d_in[7];
  const float* ve_scale   = (const float*)d_in[8];
  const float* Wq         = (const float*)d_in[9];
  const float* Wk         = (const float*)d_in[10];
  const float* Wv         = (const float*)d_in[11];
  const float* Wo         = (const float*)d_in[12];
  const float* q_gain     = (const float*)d_in[13];
  const float* attn_scale = (const float*)d_in[14];
  const float* mlp_scale  = (const float*)d_in[15];
  const float* resid_mix  = (const float*)d_in[16];
  const float* Wfc        = (const float*)d_in[17];
  const float* Wp         = (const float*)d_in[18];
  const float* head_w     = (const float*)d_in[19];
  float* out = (float*)d_out;

  float* ws = (float*)d_ws;
  float* x    = ws;
  float* x0   = ws + SZ_X;
  float* x_in = ws + 2 * SZ_X;
  float* xn   = ws + 3 * SZ_X;
  float* qb   = ws + 4 * SZ_X;
  float* yb   = ws + 5 * SZ_X;
  float* kb   = ws + 6 * SZ_X;
  float* vb   = ws + 6 * SZ_X + SZ_KV;
  float* vemb = ws + 6 * SZ_X + 2 * SZ_KV;
  float* hbuf = ws + 6 * SZ_X + 3 * SZ_KV;  // SZ_H floats
  float* raw_x = hbuf;                       // alias: raw_x dead before MLP

  // 1. embedding + bigram + v_embed
  embed_kernel<<<NTOK, 256, 0, stream>>>(ids, embed_w, big_w, big_proj,
                                         big_scale, ve_w, ve_proj, ve_scale,
                                         raw_x, vemb);
  // 2. smear
  smear_kernel<<<(int)(SZ_X / 256), 256, 0, stream>>>(raw_x, smear_gate, x, x0);

  for (int l = 0; l < Lc; ++l) {
    const float* mix = resid_mix + (size_t)l * 2 * Dc;
    prelayer_kernel<<<NTOK, 256, 0, stream>>>(x, x0, mix, x_in, xn);
    // q,k,v projections
    gemm_mfma<<<dim3(NTOK / 128, Dc / 128), 256, 0, stream>>>(
        xn, Wq + (size_t)l * Dc * Dc, qb, nullptr, nullptr, NTOK, Dc, Dc, 0);
    gemm_mfma<<<dim3(NTOK / 128, KVDc / 128), 256, 0, stream>>>(
        xn, Wk + (size_t)l * KVDc * Dc, kb, nullptr, nullptr, NTOK, KVDc, Dc, 0);
    gemm_mfma<<<dim3(NTOK / 128, KVDc / 128), 256, 0, stream>>>(
        xn, Wv + (size_t)l * KVDc * Dc, vb, vemb, nullptr, NTOK, KVDc, Dc, 0);
    // per-head rms + rope + gain
    qkrope_kernel<<<NTOK, 256, 0, stream>>>(qb, kb, q_gain + (size_t)l * Hc);
    // attention
    attn_kernel<<<dim3(Tc, Bc * HKVc), 256, 0, stream>>>(qb, kb, vb, yb);
    // out proj + residual: x = x_in + attn_scale * (y @ Wo.T)
    gemm_mfma<<<dim3(NTOK / 128, Dc / 128), 256, 0, stream>>>(
        yb, Wo + (size_t)l * Dc * Dc, x, x_in, attn_scale + (size_t)l * Dc,
        NTOK, Dc, Dc, 0);
    // MLP
    rms_kernel<<<NTOK, 256, 0, stream>>>(x, xn);
    gemm_mfma<<<dim3(NTOK / 128, MLPc / 128), 256, 0, stream>>>(
        xn, Wfc + (size_t)l * MLPc * Dc, hbuf, nullptr, nullptr, NTOK, MLPc,
        Dc, 1);
    gemm_mfma<<<dim3(NTOK / 128, Dc / 128), 256, 0, stream>>>(
        hbuf, Wp + (size_t)l * Dc * MLPc, x, x, mlp_scale + (size_t)l * Dc,
        NTOK, Dc, MLPc, 0);
  }

  // final rms + head
  rms_kernel<<<NTOK, 256, 0, stream>>>(x, xn);
  gemm_mfma<<<dim3(NTOK / 128, (Vc + 127) / 128), 256, 0, stream>>>(
      xn, head_w, out, nullptr, nullptr, NTOK, Vc, Dc, 0);
}

// Round 2
// 5882.513 us; speedup vs baseline: 2.5771x; 2.2081x over previous
//
#include <hip/hip_runtime.h>
#include <hip/hip_bf16.h>

// Problem constants (match reference)
constexpr int Bc   = 2;
constexpr int Tc   = 1024;
constexpr int Vc   = 50257;
constexpr int Lc   = 8;
constexpr int Dc   = 1024;
constexpr int Hc   = 16;
constexpr int HKVc = 4;
constexpr int HDc  = 64;     // D/H
constexpr int KVDc = 256;    // HKV*HD
constexpr int MLPc = 4096;   // 4*D
constexpr int BVc  = 65536;
constexpr int BDc  = 256;
constexpr int VEDc = 128;

constexpr int NTOK = Bc * Tc;          // 2048
constexpr long SZ_X  = (long)NTOK * Dc;    // 2,097,152
constexpr long SZ_KV = (long)NTOK * KVDc;  // 524,288
constexpr long SZ_H  = (long)NTOK * MLPc;  // 8,388,608

#define NEG_BIG (-3.0e38f)

typedef __attribute__((ext_vector_type(8))) short short8;   // 8 bf16 (4 VGPRs)
typedef __attribute__((ext_vector_type(4))) short short4v;  // 4 bf16 (8 B)
typedef __attribute__((ext_vector_type(4))) float floatx4;  // MFMA acc

__device__ __forceinline__ float wave_sum(float v) {
#pragma unroll
  for (int off = 32; off >= 1; off >>= 1) v += __shfl_xor(v, off);
  return v;
}

// Bijective XCD-aware swizzle (m204 formula): blocks resident on one XCD get
// contiguous virtual ids -> same-N-panel M-blocks share that XCD's L2.
__device__ __forceinline__ void xcd_swizzle(int& bx, int& by, int nbx, int nby) {
  int n = nbx * nby;
  int lin = by * nbx + bx;
  int q = n >> 3, rm = n & 7;
  int xcd = lin & 7, idx = lin >> 3;
  int v = (xcd < rm) ? (xcd * (q + 1) + idx)
                     : (rm * (q + 1) + (xcd - rm) * q + idx);
  bx = v % nbx;
  by = v / nbx;
}

// ---------------------------------------------------------------------------
// Embedding: raw_x = rms(embed_w[id]) + big_w[bg] @ big_proj.T * big_scale
//            vemb  = ve_w[id] @ ve_proj.T * ve_scale
// ---------------------------------------------------------------------------
__global__ __launch_bounds__(256) void embed_kernel(
    const int* __restrict__ ids, const float* __restrict__ embed_w,
    const float* __restrict__ big_w, const float* __restrict__ big_proj,
    const float* __restrict__ big_scale, const float* __restrict__ ve_w,
    const float* __restrict__ ve_proj, const float* __restrict__ ve_scale,
    float* __restrict__ raw_x, float* __restrict__ vemb) {
  int bt = blockIdx.x;
  int tid = threadIdx.x;
  int t = bt % Tc;
  int tok = ids[bt];

  const float* e = embed_w + (size_t)tok * Dc;
  float ev[4];
  float ss = 0.f;
#pragma unroll
  for (int i = 0; i < 4; ++i) {
    ev[i] = e[tid + i * 256];
    ss += ev[i] * ev[i];
  }
  __shared__ float red[4];
  __shared__ float brow[BDc];
  __shared__ float verow[VEDc];
  float wsum = wave_sum(ss);
  if ((tid & 63) == 0) red[tid >> 6] = wsum;

  int bg;
  if (t == 0) {
    bg = BVc - 1;
  } else {
    unsigned a = (unsigned)ids[bt];
    unsigned p = (unsigned)ids[bt - 1];
    bg = (int)(((36313u * a) ^ (27191u * p)) % 65535u);
  }
  brow[tid] = big_w[(size_t)bg * BDc + tid];
  if (tid < VEDc) verow[tid] = ve_w[(size_t)tok * VEDc + tid];
  __syncthreads();

  float tot = red[0] + red[1] + red[2] + red[3];
  float rn = rsqrtf(tot / (float)Dc + 1e-6f);
  float bs = big_scale[0];
#pragma unroll
  for (int i = 0; i < 4; ++i) {
    int d = tid + i * 256;
    const float* bp = big_proj + (size_t)d * BDc;
    float dot = 0.f;
    for (int c = 0; c < BDc; ++c) dot += brow[c] * bp[c];
    raw_x[(size_t)bt * Dc + d] = ev[i] * rn + dot * bs;
  }
  {
    float vs = ve_scale[0];
    int d = tid;
    const float* vp = ve_proj + (size_t)d * VEDc;
    float dot = 0.f;
    for (int c = 0; c < VEDc; ++c) dot += verow[c] * vp[c];
    vemb[(size_t)bt * KVDc + d] = dot * vs;
  }
}

// ---------------------------------------------------------------------------
// Smear: x = (1-g)*raw + g*raw_prev_token ; x0 = x
// ---------------------------------------------------------------------------
__global__ __launch_bounds__(256) void smear_kernel(
    const float* __restrict__ raw, const float* __restrict__ gate,
    float* __restrict__ x, float* __restrict__ x0) {
  long idx = (long)blockIdx.x * 256 + threadIdx.x;
  if (idx >= SZ_X) return;
  int d = (int)(idx & (Dc - 1));
  int t = (int)((idx / Dc) & (Tc - 1));
  float g = 1.f / (1.f + expf(-gate[d]));
  float cur = raw[idx];
  float prev = (t > 0) ? raw[idx - Dc] : 0.f;
  float val = (1.f - g) * cur + g * prev;
  x[idx] = val;
  x0[idx] = val;
}

// ---------------------------------------------------------------------------
// Pre-layer: x_in = mix0*x + mix1*x0 ; xn = rms(x_in). Block per token.
// ---------------------------------------------------------------------------
__global__ __launch_bounds__(256) void prelayer_kernel(
    const float* __restrict__ x, const float* __restrict__ x0,
    const float* __restrict__ mix, float* __restrict__ x_in,
    float* __restrict__ xn) {
  int bt = blockIdx.x;
  int tid = threadIdx.x;
  const float* xr = x + (size_t)bt * Dc;
  const float* x0r = x0 + (size_t)bt * Dc;
  float vals[4];
  float ss = 0.f;
#pragma unroll
  for (int i = 0; i < 4; ++i) {
    int d = tid + i * 256;
    float v = mix[d] * xr[d] + mix[Dc + d] * x0r[d];
    vals[i] = v;
    ss += v * v;
  }
  __shared__ float red[4];
  float wsum = wave_sum(ss);
  if ((tid & 63) == 0) red[tid >> 6] = wsum;
  __syncthreads();
  float tot = red[0] + red[1] + red[2] + red[3];
  float rn = rsqrtf(tot / (float)Dc + 1e-6f);
#pragma unroll
  for (int i = 0; i < 4; ++i) {
    int d = tid + i * 256;
    x_in[(size_t)bt * Dc + d] = vals[i];
    xn[(size_t)bt * Dc + d] = vals[i] * rn;
  }
}

// ---------------------------------------------------------------------------
// Plain RMS over D. Block per token.
// ---------------------------------------------------------------------------
__global__ __launch_bounds__(256) void rms_kernel(const float* __restrict__ in,
                                                  float* __restrict__ out) {
  int bt = blockIdx.x;
  int tid = threadIdx.x;
  const float* p = in + (size_t)bt * Dc;
  float v[4];
  float ss = 0.f;
#pragma unroll
  for (int i = 0; i < 4; ++i) {
    v[i] = p[tid + i * 256];
    ss += v[i] * v[i];
  }
  __shared__ float red[4];
  float wsum = wave_sum(ss);
  if ((tid & 63) == 0) red[tid >> 6] = wsum;
  __syncthreads();
  float tot = red[0] + red[1] + red[2] + red[3];
  float rn = rsqrtf(tot / (float)Dc + 1e-6f);
  float* o = out + (size_t)bt * Dc;
#pragma unroll
  for (int i = 0; i < 4; ++i) o[tid + i * 256] = v[i] * rn;
}

// ---------------------------------------------------------------------------
// bf16 split helpers: f = bf2f(hi) + bf2f(lo) + O(2^-17 * f)
// ---------------------------------------------------------------------------
__device__ __forceinline__ short f2bf(float f) {
  unsigned u = __float_as_uint(f);
  return (short)((u + 0x7fffu + ((u >> 16) & 1u)) >> 16);
}
__device__ __forceinline__ float bf2f(short h) {
  return __uint_as_float(((unsigned)(unsigned short)h) << 16);
}
__device__ __forceinline__ void cvt_store(short* hp, short* lp, float4 f0,
                                          float4 f1) {
  float fv[8] = {f0.x, f0.y, f0.z, f0.w, f1.x, f1.y, f1.z, f1.w};
  short8 hi, lo;
#pragma unroll
  for (int i = 0; i < 8; ++i) {
    short h = f2bf(fv[i]);
    hi[i] = h;
    lo[i] = f2bf(fv[i] - bf2f(h));
  }
  *(short8*)hp = hi;
  *(short8*)lp = lo;
}

// ---------------------------------------------------------------------------
// MFMA GEMM 128x128 (bf16x2 split): C[M,N] = epi( A[M,K] @ W[N,K].T )
// ---------------------------------------------------------------------------
__global__ __launch_bounds__(256) void gemm_mfma(
    const float* __restrict__ A, const float* __restrict__ W,
    float* __restrict__ C, const float* __restrict__ base,
    const float* __restrict__ colscale, int M, int N, int K, int act) {
  __shared__ short lds[16384];  // 32 KiB
  short* As_hi = lds;
  short* As_lo = lds + 4096;
  short* Bs_hi = lds + 8192;
  short* Bs_lo = lds + 12288;
  int tid = threadIdx.x;
  int lane = tid & 63, wv = tid >> 6;
  int wm = (wv >> 1) * 64, wn = (wv & 1) * 64;
  int bx = blockIdx.x, by = blockIdx.y;
  xcd_swizzle(bx, by, gridDim.x, gridDim.y);
  int m0 = bx * 128, n0 = by * 128;

  floatx4 acc[4][4] = {};

  for (int k0 = 0; k0 < K; k0 += 32) {
#pragma unroll
    for (int cc = 0; cc < 2; ++cc) {
      int c = tid + cc * 256;
      int r = c >> 2;
      int kg = c & 3;
      int off = (r >> 4) * 512 + ((r & 15) + kg * 16) * 8;
      {
        const float* src = A + (size_t)(m0 + r) * K + k0 + kg * 8;
        float4 f0 = *(const float4*)src;
        float4 f1 = *(const float4*)(src + 4);
        cvt_store(As_hi + off, As_lo + off, f0, f1);
      }
      {
        int gn = n0 + r;
        float4 f0 = make_float4(0.f, 0.f, 0.f, 0.f), f1 = f0;
        if (gn < N) {
          const float* src = W + (size_t)gn * K + k0 + kg * 8;
          f0 = *(const float4*)src;
          f1 = *(const float4*)(src + 4);
        }
        cvt_store(Bs_hi + off, Bs_lo + off, f0, f1);
      }
    }
    __syncthreads();
    short8 ah[4], al[4], bh[4], bl[4];
    int ab = wm >> 4, bb = wn >> 4;
#pragma unroll
    for (int i = 0; i < 4; ++i) {
      int offa = (ab + i) * 512 + lane * 8;
      ah[i] = *(const short8*)(As_hi + offa);
      al[i] = *(const short8*)(As_lo + offa);
      int offb = (bb + i) * 512 + lane * 8;
      bh[i] = *(const short8*)(Bs_hi + offb);
      bl[i] = *(const short8*)(Bs_lo + offb);
    }
#pragma unroll
    for (int i = 0; i < 4; ++i)
#pragma unroll
      for (int j = 0; j < 4; ++j) {
        acc[i][j] =
            __builtin_amdgcn_mfma_f32_16x16x32_bf16(ah[i], bh[j], acc[i][j], 0, 0, 0);
        acc[i][j] =
            __builtin_amdgcn_mfma_f32_16x16x32_bf16(ah[i], bl[j], acc[i][j], 0, 0, 0);
        acc[i][j] =
            __builtin_amdgcn_mfma_f32_16x16x32_bf16(al[i], bh[j], acc[i][j], 0, 0, 0);
      }
    __syncthreads();
  }
#pragma unroll
  for (int i = 0; i < 4; ++i) {
#pragma unroll
    for (int j = 0; j < 4; ++j) {
      int col = n0 + wn + 16 * j + (lane & 15);
      if (col >= N) continue;
      int row0 = m0 + wm + 16 * i + (lane >> 4) * 4;
      floatx4 f = acc[i][j];
#pragma unroll
      for (int r = 0; r < 4; ++r) {
        float v = f[r];
        if (act == 1) {
          float h = (v >= 0.f) ? v : 0.5f * v;
          v = h * h;
        }
        if (colscale) v *= colscale[col];
        size_t idx = (size_t)(row0 + r) * N + col;
        if (base) v += base[idx];
        C[idx] = v;
      }
    }
  }
}

// ---------------------------------------------------------------------------
// MFMA GEMM 64x64 tile body (bf16x2). 4 waves, each 32x32. Full tiles only.
// ---------------------------------------------------------------------------
__device__ __forceinline__ void gemm64_body(
    const float* __restrict__ A, const float* __restrict__ W,
    float* __restrict__ C, const float* __restrict__ base,
    const float* __restrict__ colscale, int K, int act, int m0, int n0, int N,
    short* lds) {
  short* As_hi = lds;
  short* As_lo = lds + 2048;
  short* Bs_hi = lds + 4096;
  short* Bs_lo = lds + 6144;
  int tid = threadIdx.x;
  int lane = tid & 63, wv = tid >> 6;
  int wm = (wv >> 1) * 32, wn = (wv & 1) * 32;
  floatx4 acc[2][2] = {};
  int r = tid >> 2, kgl = tid & 3;
  int off = (r >> 4) * 512 + ((r & 15) + kgl * 16) * 8;
  for (int k0 = 0; k0 < K; k0 += 32) {
    {
      const float* src = A + (size_t)(m0 + r) * K + k0 + kgl * 8;
      float4 f0 = *(const float4*)src, f1 = *(const float4*)(src + 4);
      cvt_store(As_hi + off, As_lo + off, f0, f1);
    }
    {
      const float* src = W + (size_t)(n0 + r) * K + k0 + kgl * 8;
      float4 f0 = *(const float4*)src, f1 = *(const float4*)(src + 4);
      cvt_store(Bs_hi + off, Bs_lo + off, f0, f1);
    }
    __syncthreads();
    short8 ah[2], al_[2], bh[2], bl_[2];
#pragma unroll
    for (int i = 0; i < 2; ++i) {
      int oa = ((wm >> 4) + i) * 512 + lane * 8;
      ah[i] = *(const short8*)(As_hi + oa);
      al_[i] = *(const short8*)(As_lo + oa);
      int ob = ((wn >> 4) + i) * 512 + lane * 8;
      bh[i] = *(const short8*)(Bs_hi + ob);
      bl_[i] = *(const short8*)(Bs_lo + ob);
    }
#pragma unroll
    for (int i = 0; i < 2; ++i)
#pragma unroll
      for (int j = 0; j < 2; ++j) {
        acc[i][j] = __builtin_amdgcn_mfma_f32_16x16x32_bf16(ah[i], bh[j], acc[i][j], 0, 0, 0);
        acc[i][j] = __builtin_amdgcn_mfma_f32_16x16x32_bf16(ah[i], bl_[j], acc[i][j], 0, 0, 0);
        acc[i][j] = __builtin_amdgcn_mfma_f32_16x16x32_bf16(al_[i], bh[j], acc[i][j], 0, 0, 0);
      }
    __syncthreads();
  }
  int x = lane & 15, g = lane >> 4;
#pragma unroll
  for (int i = 0; i < 2; ++i) {
#pragma unroll
    for (int j = 0; j < 2; ++j) {
      int col = n0 + wn + 16 * j + x;
      int row0 = m0 + wm + 16 * i + 4 * g;
      floatx4 f = acc[i][j];
#pragma unroll
      for (int rr = 0; rr < 4; ++rr) {
        float v = f[rr];
        if (act == 1) {
          float hh = (v >= 0.f) ? v : 0.5f * v;
          v = hh * hh;
        }
        if (colscale) v *= colscale[col];
        size_t idx = (size_t)(row0 + rr) * N + col;
        if (base) v += base[idx];
        C[idx] = v;
      }
    }
  }
}

__global__ __launch_bounds__(256) void gemm64_kernel(
    const float* __restrict__ A, const float* __restrict__ W,
    float* __restrict__ C, const float* __restrict__ base,
    const float* __restrict__ colscale, int N, int K, int act) {
  __shared__ short lds[8192];
  int bx = blockIdx.x, by = blockIdx.y;
  xcd_swizzle(bx, by, gridDim.x, gridDim.y);
  gemm64_body(A, W, C, base, colscale, K, act, bx * 64, by * 64, N, lds);
}

// Fused K+V projection: grid (M/64, 8); by<4 -> K panel, by>=4 -> V panel.
__global__ __launch_bounds__(256) void gemm64_kv_kernel(
    const float* __restrict__ A, const float* __restrict__ Wk_,
    const float* __restrict__ Wv_, float* __restrict__ Ck,
    float* __restrict__ Cv, const float* __restrict__ vemb, int K) {
  __shared__ short lds[8192];
  int bx = blockIdx.x, by = blockIdx.y;
  xcd_swizzle(bx, by, gridDim.x, gridDim.y);
  int sel = by >> 2, byl = by & 3;
  const float* W = sel ? Wv_ : Wk_;
  float* C = sel ? Cv : Ck;
  const float* base = sel ? vemb : nullptr;
  gemm64_body(A, W, C, base, nullptr, K, 0, bx * 64, byl * 64, KVDc, lds);
}

// ---------------------------------------------------------------------------
// QK head-RMS + RoPE (+q_gain). Block per token.
// ---------------------------------------------------------------------------
__global__ __launch_bounds__(256) void qkrope_kernel(
    float* __restrict__ q, float* __restrict__ k,
    const float* __restrict__ q_gain) {
  int bt = blockIdx.x;
  int t = bt % Tc;
  int tid = threadIdx.x;
  int lane = tid & 63, wv = tid >> 6;
  int fi = lane & 31;
  float inv = expf(-(float)(2 * fi) * (9.210340372f / 64.f));
  float ang = (float)t * inv;
  float cv = cosf(ang);
  float sv = sinf(ang);

#pragma unroll
  for (int hh = 0; hh < 4; ++hh) {
    int h = wv + hh * 4;
    float* qp = q + (size_t)bt * Dc + h * 64;
    float val = qp[lane];
    float ss = wave_sum(val * val);
    float rn = rsqrtf(ss / 64.f + 1e-6f);
    val *= rn;
    float partner = __shfl(val, lane ^ 32);
    float out = (lane < 32) ? (val * cv + partner * sv) : (val * cv - partner * sv);
    out *= q_gain[h];
    qp[lane] = out;
  }
  {
    int h = wv;
    float* kp = k + (size_t)bt * KVDc + h * 64;
    float val = kp[lane];
    float ss = wave_sum(val * val);
    float rn = rsqrtf(ss / 64.f + 1e-6f);
    val *= rn;
    float partner = __shfl(val, lane ^ 32);
    float out = (lane < 32) ? (val * cv + partner * sv) : (val * cv - partner * sv);
    kp[lane] = out;
  }
}

// ---------------------------------------------------------------------------
// MFMA causal GQA flash attention + v-direction-removal epilogue.
// Grid (Tc/32, Bc*HKVc). Block 256 = 4 waves = the 4 q-heads of one kv head,
// covering 32 q rows. Per K-tile (64 keys):
//   S^T[k,q] = mfma(A=K rows, B=Q rows)  (bf16 hi/lo split, fp32-level acc)
//   online softmax on S^T columns (q) via 2x shfl_xor reduction
//   P bounced through per-wave LDS in A-frag lane order (conflict-free b128)
//   O[q,d] = mfma(A=P, B=V^T rows)  with V staged transposed in LDS
// ---------------------------------------------------------------------------
__global__ __launch_bounds__(256) void attn_mfma(
    const float* __restrict__ qg_, const float* __restrict__ kg_,
    const float* __restrict__ vg_, float* __restrict__ yg_) {
  __shared__ short smem[32768];  // 64 KiB
  short* Khi  = smem;
  short* Klo  = smem + 4096;
  short* Vthi = smem + 8192;
  short* Vtlo = smem + 12288;

  int qt = blockIdx.x;   // 0..31
  int bh = blockIdx.y;   // 0..7
  int b = bh >> 2, hkv = bh & 3;
  int tid = threadIdx.x;
  int lane = tid & 63, wv = tid >> 6;
  int x = lane & 15, g = lane >> 4;
  int h = hkv * 4 + wv;
  int qbase = qt * 32;

  short* PAhi = smem + 16384 + wv * 2048;
  short* PAlo = smem + 24576 + wv * 2048;

  // Q fragments in registers (rows 16j+x, d-octet g, d-step ks)
  short8 qh[2][2], qlo[2][2];
#pragma unroll
  for (int j = 0; j < 2; ++j)
#pragma unroll
    for (int ks = 0; ks < 2; ++ks) {
      int qrow = qbase + 16 * j + x;
      const float* qp =
          qg_ + ((size_t)(b * Tc + qrow)) * Dc + h * 64 + ks * 32 + g * 8;
      float4 f0 = *(const float4*)qp;
      float4 f1 = *(const float4*)(qp + 4);
      float fv[8] = {f0.x, f0.y, f0.z, f0.w, f1.x, f1.y, f1.z, f1.w};
#pragma unroll
      for (int e = 0; e < 8; ++e) {
        short hb = f2bf(fv[e]);
        qh[j][ks][e] = hb;
        qlo[j][ks][e] = f2bf(fv[e] - bf2f(hb));
      }
    }

  floatx4 o[2][4] = {};
  float m_run[2] = {NEG_BIG, NEG_BIG};
  float l_run[2] = {0.f, 0.f};

  int nkt = (qbase >> 6) + 1;
  for (int kt = 0; kt < nkt; ++kt) {
    // ---- stage K (row-major frag order, hi/lo) ----
    {
      int r = tid >> 2, kgl = tid & 3;
#pragma unroll
      for (int half = 0; half < 2; ++half) {
        int d0 = kgl * 8 + half * 32;
        const float* src =
            kg_ + ((size_t)(b * Tc + kt * 64 + r)) * KVDc + hkv * 64 + d0;
        float4 f0 = *(const float4*)src;
        float4 f1 = *(const float4*)(src + 4);
        int off = half * 2048 + (r >> 4) * 512 + ((r & 15) + kgl * 16) * 8;
        cvt_store(Khi + off, Klo + off, f0, f1);
      }
    }
    // ---- stage V transposed: Vt[d][k], column-wise gather ----
    {
      int d = 16 * wv + x;  // row of Vt
#pragma unroll
      for (int ks = 0; ks < 2; ++ks) {
        float fv[8];
#pragma unroll
        for (int e = 0; e < 8; ++e) {
          int kk = ks * 32 + g * 8 + e;
          fv[e] = vg_[((size_t)(b * Tc + kt * 64 + kk)) * KVDc + hkv * 64 + d];
        }
        short8 hi8, lo8;
#pragma unroll
        for (int e = 0; e < 8; ++e) {
          short hb = f2bf(fv[e]);
          hi8[e] = hb;
          lo8[e] = f2bf(fv[e] - bf2f(hb));
        }
        int off = ks * 2048 + wv * 512 + (x + g * 16) * 8;
        *(short8*)(Vthi + off) = hi8;
        *(short8*)(Vtlo + off) = lo8;
      }
    }
    __syncthreads();

    // ---- S^T = K · Q^T ----
    floatx4 st[4][2] = {};
#pragma unroll
    for (int ks = 0; ks < 2; ++ks) {
#pragma unroll
      for (int i = 0; i < 4; ++i) {
        short8 ka_h = *(const short8*)(Khi + ks * 2048 + i * 512 + lane * 8);
        short8 ka_l = *(const short8*)(Klo + ks * 2048 + i * 512 + lane * 8);
#pragma unroll
        for (int j = 0; j < 2; ++j) {
          st[i][j] = __builtin_amdgcn_mfma_f32_16x16x32_bf16(ka_h, qh[j][ks], st[i][j], 0, 0, 0);
          st[i][j] = __builtin_amdgcn_mfma_f32_16x16x32_bf16(ka_h, qlo[j][ks], st[i][j], 0, 0, 0);
          st[i][j] = __builtin_amdgcn_mfma_f32_16x16x32_bf16(ka_l, qh[j][ks], st[i][j], 0, 0, 0);
        }
      }
    }

    // ---- mask + online softmax (per q column) ----
    float al[2];
#pragma unroll
    for (int j = 0; j < 2; ++j) {
      int qrow = qbase + 16 * j + x;
      float mx = NEG_BIG;
#pragma unroll
      for (int i = 0; i < 4; ++i) {
#pragma unroll
        for (int r = 0; r < 4; ++r) {
          int krow = kt * 64 + 16 * i + 4 * g + r;
          float s = st[i][j][r] * 0.125f;
          if (krow > qrow) s = NEG_BIG;
          st[i][j][r] = s;
          mx = fmaxf(mx, s);
        }
      }
      mx = fmaxf(mx, __shfl_xor(mx, 16));
      mx = fmaxf(mx, __shfl_xor(mx, 32));
      float m_new = fmaxf(m_run[j], mx);
      al[j] = __expf(m_run[j] - m_new);
      float ts = 0.f;
#pragma unroll
      for (int i = 0; i < 4; ++i) {
#pragma unroll
        for (int r = 0; r < 4; ++r) {
          float p = __expf(st[i][j][r] - m_new);
          st[i][j][r] = p;
          ts += p;
        }
      }
      ts += __shfl_xor(ts, 16);
      ts += __shfl_xor(ts, 32);
      l_run[j] = l_run[j] * al[j] + ts;
      m_run[j] = m_new;
    }

    // ---- write P to per-wave LDS in A-frag order (hi/lo) ----
#pragma unroll
    for (int j = 0; j < 2; ++j) {
#pragma unroll
      for (int i = 0; i < 4; ++i) {
        short4v h4, l4;
#pragma unroll
        for (int r = 0; r < 4; ++r) {
          float p = st[i][j][r];
          short hb = f2bf(p);
          h4[r] = hb;
          l4[r] = f2bf(p - bf2f(hb));
        }
        int offp = (i >> 1) * 1024 + j * 512 +
                   (x + (2 * (i & 1) + (g >> 1)) * 16) * 8 + 4 * (g & 1);
        *(short4v*)(PAhi + offp) = h4;
        *(short4v*)(PAlo + offp) = l4;
      }
    }

    // ---- rescale O by alpha (O rows q = 16*iO + 4g + r) ----
#pragma unroll
    for (int iO = 0; iO < 2; ++iO) {
#pragma unroll
      for (int r = 0; r < 4; ++r) {
        float a = __shfl(al[iO], 4 * g + r);
#pragma unroll
        for (int jd = 0; jd < 4; ++jd) o[iO][jd][r] *= a;
      }
    }
    __syncthreads();

    // ---- O += P · V ----
#pragma unroll
    for (int ks = 0; ks < 2; ++ks) {
      short8 pa_h[2], pa_l[2];
#pragma unroll
      for (int iO = 0; iO < 2; ++iO) {
        pa_h[iO] = *(const short8*)(PAhi + ks * 1024 + iO * 512 + lane * 8);
        pa_l[iO] = *(const short8*)(PAlo + ks * 1024 + iO * 512 + lane * 8);
      }
#pragma unroll
      for (int jd = 0; jd < 4; ++jd) {
        short8 vb_h = *(const short8*)(Vthi + ks * 2048 + jd * 512 + lane * 8);
        short8 vb_l = *(const short8*)(Vtlo + ks * 2048 + jd * 512 + lane * 8);
#pragma unroll
        for (int iO = 0; iO < 2; ++iO) {
          o[iO][jd] = __builtin_amdgcn_mfma_f32_16x16x32_bf16(pa_h[iO], vb_h, o[iO][jd], 0, 0, 0);
          o[iO][jd] = __builtin_amdgcn_mfma_f32_16x16x32_bf16(pa_h[iO], vb_l, o[iO][jd], 0, 0, 0);
          o[iO][jd] = __builtin_amdgcn_mfma_f32_16x16x32_bf16(pa_l[iO], vb_h, o[iO][jd], 0, 0, 0);
        }
      }
    }
    __syncthreads();
  }

  // ---- finalize: /l_run, remove component along normalized v, store ----
#pragma unroll
  for (int iO = 0; iO < 2; ++iO) {
#pragma unroll
    for (int r = 0; r < 4; ++r) {
      float lr = __shfl(l_run[iO], 4 * g + r);
      float rcp = 1.f / lr;
      int qrow = qbase + 16 * iO + 4 * g + r;
      const float* vr = vg_ + ((size_t)(b * Tc + qrow)) * KVDc + hkv * 64;
      float vv[4], oo[4];
      float pn = 0.f, pd = 0.f;
#pragma unroll
      for (int jd = 0; jd < 4; ++jd) {
        vv[jd] = vr[16 * jd + x];
        oo[jd] = o[iO][jd][r] * rcp;
        pn += vv[jd] * vv[jd];
        pd += oo[jd] * vv[jd];
      }
#pragma unroll
      for (int off = 1; off <= 8; off <<= 1) {
        pn += __shfl_xor(pn, off);
        pd += __shfl_xor(pd, off);
      }
      float nrm = sqrtf(pn);
      float mxv = fmaxf(nrm, 1e-12f);
      float si = 1.f / mxv;
      float co = pd * si * si;
      float* yr = yg_ + ((size_t)(b * Tc + qrow)) * Dc + h * 64;
#pragma unroll
      for (int jd = 0; jd < 4; ++jd) yr[16 * jd + x] = oo[jd] - co * vv[jd];
    }
  }
}

// ---------------------------------------------------------------------------
extern "C" void kernel_launch(void* const* d_in, const int* in_sizes, int n_in,
                              void* d_out, int out_size, void* d_ws,
                              size_t ws_size, hipStream_t stream) {
  const int* ids          = (const int*)d_in[0];
  const float* embed_w    = (const float*)d_in[1];
  const float* big_w      = (const float*)d_in[2];
  const float* big_proj   = (const float*)d_in[3];
  const float* big_scale  = (const float*)d_in[4];
  const float* smear_gate = (const float*)d_in[5];
  const float* ve_w       = (const float*)d_in[6];
  const float* ve_proj    = (const float*)d_in[7];
  const float* ve_scale   = (const float*)d_in[8];
  const float* Wq         = (const float*)d_in[9];
  const float* Wk         = (const float*)d_in[10];
  const float* Wv         = (const float*)d_in[11];
  const float* Wo         = (const float*)d_in[12];
  const float* q_gain     = (const float*)d_in[13];
  const float* attn_scale = (const float*)d_in[14];
  const float* mlp_scale  = (const float*)d_in[15];
  const float* resid_mix  = (const float*)d_in[16];
  const float* Wfc        = (const float*)d_in[17];
  const float* Wp         = (const float*)d_in[18];
  const float* head_w     = (const float*)d_in[19];
  float* out = (float*)d_out;

  float* ws = (float*)d_ws;
  float* x    = ws;
  float* x0   = ws + SZ_X;
  float* x_in = ws + 2 * SZ_X;
  float* xn   = ws + 3 * SZ_X;
  float* qb   = ws + 4 * SZ_X;
  float* yb   = ws + 5 * SZ_X;
  float* kb   = ws + 6 * SZ_X;
  float* vb   = ws + 6 * SZ_X + SZ_KV;
  float* vemb = ws + 6 * SZ_X + 2 * SZ_KV;
  float* hbuf = ws + 6 * SZ_X + 3 * SZ_KV;  // SZ_H floats
  float* raw_x = hbuf;                       // alias: raw_x dead before MLP

  embed_kernel<<<NTOK, 256, 0, stream>>>(ids, embed_w, big_w, big_proj,
                                         big_scale, ve_w, ve_proj, ve_scale,
                                         raw_x, vemb);
  smear_kernel<<<(int)(SZ_X / 256), 256, 0, stream>>>(raw_x, smear_gate, x, x0);

  for (int l = 0; l < Lc; ++l) {
    const float* mix = resid_mix + (size_t)l * 2 * Dc;
    prelayer_kernel<<<NTOK, 256, 0, stream>>>(x, x0, mix, x_in, xn);
    // q projection
    gemm64_kernel<<<dim3(NTOK / 64, Dc / 64), 256, 0, stream>>>(
        xn, Wq + (size_t)l * Dc * Dc, qb, nullptr, nullptr, Dc, Dc, 0);
    // fused k,v projections
    gemm64_kv_kernel<<<dim3(NTOK / 64, 8), 256, 0, stream>>>(
        xn, Wk + (size_t)l * KVDc * Dc, Wv + (size_t)l * KVDc * Dc, kb, vb,
        vemb, Dc);
    qkrope_kernel<<<NTOK, 256, 0, stream>>>(qb, kb, q_gain + (size_t)l * Hc);
    attn_mfma<<<dim3(Tc / 32, Bc * HKVc), 256, 0, stream>>>(qb, kb, vb, yb);
    // out proj + residual
    gemm64_kernel<<<dim3(NTOK / 64, Dc / 64), 256, 0, stream>>>(
        yb, Wo + (size_t)l * Dc * Dc, x, x_in, attn_scale + (size_t)l * Dc, Dc,
        Dc, 0);
    // MLP
    rms_kernel<<<NTOK, 256, 0, stream>>>(x, xn);
    gemm_mfma<<<dim3(NTOK / 128, MLPc / 128), 256, 0, stream>>>(
        xn, Wfc + (size_t)l * MLPc * Dc, hbuf, nullptr, nullptr, NTOK, MLPc,
        Dc, 1);
    gemm64_kernel<<<dim3(NTOK / 64, Dc / 64), 256, 0, stream>>>(
        hbuf, Wp + (size_t)l * Dc * MLPc, x, x, mlp_scale + (size_t)l * Dc, Dc,
        MLPc, 0);
  }

  rms_kernel<<<NTOK, 256, 0, stream>>>(x, xn);
  gemm_mfma<<<dim3(NTOK / 128, (Vc + 127) / 128), 256, 0, stream>>>(
      xn, head_w, out, nullptr, nullptr, NTOK, Vc, Dc, 0);
}

// Round 3
// 5603.902 us; speedup vs baseline: 2.7052x; 1.0497x over previous
//
#include <hip/hip_runtime.h>
#include <hip/hip_bf16.h>

// Problem constants (match reference)
constexpr int Bc   = 2;
constexpr int Tc   = 1024;
constexpr int Vc   = 50257;
constexpr int Lc   = 8;
constexpr int Dc   = 1024;
constexpr int Hc   = 16;
constexpr int HKVc = 4;
constexpr int HDc  = 64;     // D/H
constexpr int KVDc = 256;    // HKV*HD
constexpr int MLPc = 4096;   // 4*D
constexpr int BVc  = 65536;
constexpr int BDc  = 256;
constexpr int VEDc = 128;

constexpr int NTOK = Bc * Tc;          // 2048
constexpr long SZ_X  = (long)NTOK * Dc;    // 2,097,152
constexpr long SZ_KV = (long)NTOK * KVDc;  // 524,288
constexpr long SZ_H  = (long)NTOK * MLPc;  // 8,388,608

constexpr long W_Q  = (long)Lc * Dc * Dc;     // 8,388,608
constexpr long W_KV = (long)Lc * KVDc * Dc;   // 2,097,152
constexpr long W_FC = (long)Lc * MLPc * Dc;   // 33,554,432
constexpr long W_HD = (long)Vc * Dc;          // 51,463,168

#define NEG_BIG (-3.0e38f)

typedef __attribute__((ext_vector_type(8))) short short8;   // 8 bf16 (4 VGPRs)
typedef __attribute__((ext_vector_type(4))) short short4v;  // 4 bf16 (8 B)
typedef __attribute__((ext_vector_type(4))) float floatx4;  // MFMA acc

__device__ __forceinline__ float wave_sum(float v) {
#pragma unroll
  for (int off = 32; off >= 1; off >>= 1) v += __shfl_xor(v, off);
  return v;
}

// Bijective XCD-aware swizzle (m204 formula).
__device__ __forceinline__ void xcd_swizzle(int& bx, int& by, int nbx, int nby) {
  int n = nbx * nby;
  int lin = by * nbx + bx;
  int q = n >> 3, rm = n & 7;
  int xcd = lin & 7, idx = lin >> 3;
  int v = (xcd < rm) ? (xcd * (q + 1) + idx)
                     : (rm * (q + 1) + (xcd - rm) * q + idx);
  bx = v % nbx;
  by = v / nbx;
}

// async global->LDS, 16B per lane. LDS dest = uniform base + lane*16.
__device__ __forceinline__ void gll16(const void* g, void* l) {
  __builtin_amdgcn_global_load_lds(
      (const __attribute__((address_space(1))) unsigned int*)g,
      (__attribute__((address_space(3))) unsigned int*)l, 16, 0, 0);
}

// ---------------------------------------------------------------------------
// bf16 split helpers: f = bf2f(hi) + bf2f(lo) + O(2^-17 * f)
// ---------------------------------------------------------------------------
__device__ __forceinline__ short f2bf(float f) {
  unsigned u = __float_as_uint(f);
  return (short)((u + 0x7fffu + ((u >> 16) & 1u)) >> 16);
}
__device__ __forceinline__ float bf2f(short h) {
  return __uint_as_float(((unsigned)(unsigned short)h) << 16);
}

// ---------------------------------------------------------------------------
// Weight conversion: fp32 -> (hi, lo) bf16 planes. 8 elems/thread.
// ---------------------------------------------------------------------------
__global__ __launch_bounds__(256) void wcvt_kernel(
    const float* __restrict__ src, short* __restrict__ hi,
    short* __restrict__ lo, long n8) {
  long i = (long)blockIdx.x * 256 + threadIdx.x;
  if (i >= n8) return;
  const float* s = src + i * 8;
  float4 f0 = *(const float4*)s;
  float4 f1 = *(const float4*)(s + 4);
  float fv[8] = {f0.x, f0.y, f0.z, f0.w, f1.x, f1.y, f1.z, f1.w};
  short8 h8, l8;
#pragma unroll
  for (int e = 0; e < 8; ++e) {
    short hb = f2bf(fv[e]);
    h8[e] = hb;
    l8[e] = f2bf(fv[e] - bf2f(hb));
  }
  *(short8*)(hi + i * 8) = h8;
  *(short8*)(lo + i * 8) = l8;
}

// ---------------------------------------------------------------------------
// Embedding: raw_x = rms(embed_w[id]) + big_w[bg] @ big_proj.T * big_scale
//            vemb  = ve_w[id] @ ve_proj.T * ve_scale
// ---------------------------------------------------------------------------
__global__ __launch_bounds__(256) void embed_kernel(
    const int* __restrict__ ids, const float* __restrict__ embed_w,
    const float* __restrict__ big_w, const float* __restrict__ big_proj,
    const float* __restrict__ big_scale, const float* __restrict__ ve_w,
    const float* __restrict__ ve_proj, const float* __restrict__ ve_scale,
    float* __restrict__ raw_x, float* __restrict__ vemb) {
  int bt = blockIdx.x;
  int tid = threadIdx.x;
  int t = bt % Tc;
  int tok = ids[bt];

  const float* e = embed_w + (size_t)tok * Dc;
  float ev[4];
  float ss = 0.f;
#pragma unroll
  for (int i = 0; i < 4; ++i) {
    ev[i] = e[tid + i * 256];
    ss += ev[i] * ev[i];
  }
  __shared__ float red[4];
  __shared__ float brow[BDc];
  __shared__ float verow[VEDc];
  float wsum = wave_sum(ss);
  if ((tid & 63) == 0) red[tid >> 6] = wsum;

  int bg;
  if (t == 0) {
    bg = BVc - 1;
  } else {
    unsigned a = (unsigned)ids[bt];
    unsigned p = (unsigned)ids[bt - 1];
    bg = (int)(((36313u * a) ^ (27191u * p)) % 65535u);
  }
  brow[tid] = big_w[(size_t)bg * BDc + tid];
  if (tid < VEDc) verow[tid] = ve_w[(size_t)tok * VEDc + tid];
  __syncthreads();

  float tot = red[0] + red[1] + red[2] + red[3];
  float rn = rsqrtf(tot / (float)Dc + 1e-6f);
  float bs = big_scale[0];
#pragma unroll
  for (int i = 0; i < 4; ++i) {
    int d = tid + i * 256;
    const float* bp = big_proj + (size_t)d * BDc;
    float dot = 0.f;
    for (int c = 0; c < BDc; ++c) dot += brow[c] * bp[c];
    raw_x[(size_t)bt * Dc + d] = ev[i] * rn + dot * bs;
  }
  {
    float vs = ve_scale[0];
    int d = tid;
    const float* vp = ve_proj + (size_t)d * VEDc;
    float dot = 0.f;
    for (int c = 0; c < VEDc; ++c) dot += verow[c] * vp[c];
    vemb[(size_t)bt * KVDc + d] = dot * vs;
  }
}

// ---------------------------------------------------------------------------
// Smear: x = (1-g)*raw + g*raw_prev_token ; x0 = x
// ---------------------------------------------------------------------------
__global__ __launch_bounds__(256) void smear_kernel(
    const float* __restrict__ raw, const float* __restrict__ gate,
    float* __restrict__ x, float* __restrict__ x0) {
  long idx = (long)blockIdx.x * 256 + threadIdx.x;
  if (idx >= SZ_X) return;
  int d = (int)(idx & (Dc - 1));
  int t = (int)((idx / Dc) & (Tc - 1));
  float g = 1.f / (1.f + expf(-gate[d]));
  float cur = raw[idx];
  float prev = (t > 0) ? raw[idx - Dc] : 0.f;
  float val = (1.f - g) * cur + g * prev;
  x[idx] = val;
  x0[idx] = val;
}

// ---------------------------------------------------------------------------
// Pre-layer: x_in = mix0*x + mix1*x0 ; xn planes = split(rms(x_in)).
// ---------------------------------------------------------------------------
__global__ __launch_bounds__(256) void prelayer_kernel(
    const float* __restrict__ x, const float* __restrict__ x0,
    const float* __restrict__ mix, float* __restrict__ x_in,
    short* __restrict__ xnh, short* __restrict__ xnl) {
  int bt = blockIdx.x;
  int tid = threadIdx.x;
  const float* xr = x + (size_t)bt * Dc;
  const float* x0r = x0 + (size_t)bt * Dc;
  float vals[4];
  float ss = 0.f;
#pragma unroll
  for (int i = 0; i < 4; ++i) {
    int d = tid + i * 256;
    float v = mix[d] * xr[d] + mix[Dc + d] * x0r[d];
    vals[i] = v;
    ss += v * v;
  }
  __shared__ float red[4];
  float wsum = wave_sum(ss);
  if ((tid & 63) == 0) red[tid >> 6] = wsum;
  __syncthreads();
  float tot = red[0] + red[1] + red[2] + red[3];
  float rn = rsqrtf(tot / (float)Dc + 1e-6f);
#pragma unroll
  for (int i = 0; i < 4; ++i) {
    int d = tid + i * 256;
    size_t idx = (size_t)bt * Dc + d;
    x_in[idx] = vals[i];
    float vn = vals[i] * rn;
    short hb = f2bf(vn);
    xnh[idx] = hb;
    xnl[idx] = f2bf(vn - bf2f(hb));
  }
}

// ---------------------------------------------------------------------------
// RMS over D -> bf16 hi/lo planes. Block per token.
// ---------------------------------------------------------------------------
__global__ __launch_bounds__(256) void rms_split_kernel(
    const float* __restrict__ in, short* __restrict__ oh,
    short* __restrict__ ol) {
  int bt = blockIdx.x;
  int tid = threadIdx.x;
  const float* p = in + (size_t)bt * Dc;
  float v[4];
  float ss = 0.f;
#pragma unroll
  for (int i = 0; i < 4; ++i) {
    v[i] = p[tid + i * 256];
    ss += v[i] * v[i];
  }
  __shared__ float red[4];
  float wsum = wave_sum(ss);
  if ((tid & 63) == 0) red[tid >> 6] = wsum;
  __syncthreads();
  float tot = red[0] + red[1] + red[2] + red[3];
  float rn = rsqrtf(tot / (float)Dc + 1e-6f);
#pragma unroll
  for (int i = 0; i < 4; ++i) {
    size_t idx = (size_t)bt * Dc + tid + i * 256;
    float vn = v[i] * rn;
    short hb = f2bf(vn);
    oh[idx] = hb;
    ol[idx] = f2bf(vn - bf2f(hb));
  }
}

// ---------------------------------------------------------------------------
// Plane GEMM 128x128 (bf16x2, global_load_lds staging):
//   C[M,N] = epi( A[M,K] @ W[N,K].T ),  A/W given as bf16 hi/lo planes.
// LDS frag order: subtile s (16 rows x 32 k) at s*1024B, lane l -> l*16B
// (row l&15, k-octet l>>4) => conflict-free b128 reads, zero cvt VALU.
// If Ch != null: write split bf16 planes (act applied) instead of fp32.
// Requires M%128==0, K%32==0. N arbitrary (B-row clamped, col-guarded).
// ---------------------------------------------------------------------------
__global__ __launch_bounds__(256) void gemm128_p(
    const short* __restrict__ Ah, const short* __restrict__ Al,
    const short* __restrict__ Bh, const short* __restrict__ Bl,
    float* __restrict__ C, short* __restrict__ Ch, short* __restrict__ Cl,
    const float* __restrict__ base, const float* __restrict__ colscale,
    int M, int N, int K, int act) {
  __shared__ short lds[16384];  // 32 KiB: Ah, Al, Bh, Bl (8 subtiles each)
  short* As_h = lds;
  short* As_l = lds + 4096;
  short* Bs_h = lds + 8192;
  short* Bs_l = lds + 12288;
  int tid = threadIdx.x, lane = tid & 63, wv = tid >> 6;
  int bx = blockIdx.x, by = blockIdx.y;
  xcd_swizzle(bx, by, gridDim.x, gridDim.y);
  int m0 = bx * 128, n0 = by * 128;
  int r = lane & 15, o = lane >> 4;
  int s0 = wv * 2, s1 = s0 + 1;
  const short* pa_h0 = Ah + (size_t)(m0 + s0 * 16 + r) * K + o * 8;
  const short* pa_l0 = Al + (size_t)(m0 + s0 * 16 + r) * K + o * 8;
  const short* pa_h1 = Ah + (size_t)(m0 + s1 * 16 + r) * K + o * 8;
  const short* pa_l1 = Al + (size_t)(m0 + s1 * 16 + r) * K + o * 8;
  int bn0 = n0 + s0 * 16 + r; if (bn0 >= N) bn0 = N - 1;
  int bn1 = n0 + s1 * 16 + r; if (bn1 >= N) bn1 = N - 1;
  const short* pb_h0 = Bh + (size_t)bn0 * K + o * 8;
  const short* pb_l0 = Bl + (size_t)bn0 * K + o * 8;
  const short* pb_h1 = Bh + (size_t)bn1 * K + o * 8;
  const short* pb_l1 = Bl + (size_t)bn1 * K + o * 8;

  int wm = (wv >> 1) * 64, wn = (wv & 1) * 64;
  int ab = wm >> 4, bb = wn >> 4;
  floatx4 acc[4][4] = {};

  for (int k0 = 0; k0 < K; k0 += 32) {
    gll16(pa_h0 + k0, As_h + s0 * 512);
    gll16(pa_h1 + k0, As_h + s1 * 512);
    gll16(pa_l0 + k0, As_l + s0 * 512);
    gll16(pa_l1 + k0, As_l + s1 * 512);
    gll16(pb_h0 + k0, Bs_h + s0 * 512);
    gll16(pb_h1 + k0, Bs_h + s1 * 512);
    gll16(pb_l0 + k0, Bs_l + s0 * 512);
    gll16(pb_l1 + k0, Bs_l + s1 * 512);
    __syncthreads();  // drains vmcnt before barrier
    short8 ah[4], al[4], bh[4], bl[4];
#pragma unroll
    for (int i = 0; i < 4; ++i) {
      ah[i] = *(const short8*)(As_h + (ab + i) * 512 + lane * 8);
      al[i] = *(const short8*)(As_l + (ab + i) * 512 + lane * 8);
      bh[i] = *(const short8*)(Bs_h + (bb + i) * 512 + lane * 8);
      bl[i] = *(const short8*)(Bs_l + (bb + i) * 512 + lane * 8);
    }
#pragma unroll
    for (int i = 0; i < 4; ++i)
#pragma unroll
      for (int j = 0; j < 4; ++j) {
        acc[i][j] = __builtin_amdgcn_mfma_f32_16x16x32_bf16(ah[i], bh[j], acc[i][j], 0, 0, 0);
        acc[i][j] = __builtin_amdgcn_mfma_f32_16x16x32_bf16(ah[i], bl[j], acc[i][j], 0, 0, 0);
        acc[i][j] = __builtin_amdgcn_mfma_f32_16x16x32_bf16(al[i], bh[j], acc[i][j], 0, 0, 0);
      }
    __syncthreads();
  }
  int x = lane & 15, g = lane >> 4;
#pragma unroll
  for (int i = 0; i < 4; ++i) {
#pragma unroll
    for (int j = 0; j < 4; ++j) {
      int col = n0 + wn + 16 * j + x;
      if (col >= N) continue;
      int row0 = m0 + wm + 16 * i + 4 * g;
      floatx4 f = acc[i][j];
#pragma unroll
      for (int rr = 0; rr < 4; ++rr) {
        float v = f[rr];
        if (act == 1) {
          float hh = (v >= 0.f) ? v : 0.5f * v;
          v = hh * hh;
        }
        if (colscale) v *= colscale[col];
        size_t idx = (size_t)(row0 + rr) * N + col;
        if (base) v += base[idx];
        if (Ch) {
          short hb = f2bf(v);
          Ch[idx] = hb;
          Cl[idx] = f2bf(v - bf2f(hb));
        } else {
          C[idx] = v;
        }
      }
    }
  }
}

// ---------------------------------------------------------------------------
// Plane GEMM 64x64 tile body. 4 waves, 32x32 each. N%64==0, M%64==0, K%32==0.
// ---------------------------------------------------------------------------
__device__ __forceinline__ void gemm64_body(
    const short* __restrict__ Ah, const short* __restrict__ Al,
    const short* __restrict__ Bh, const short* __restrict__ Bl,
    float* __restrict__ C, const float* __restrict__ base,
    const float* __restrict__ colscale, int N, int K, int act, int m0, int n0,
    short* lds) {
  short* As_h = lds;          // 4 subtiles x 512 shorts
  short* As_l = lds + 2048;
  short* Bs_h = lds + 4096;
  short* Bs_l = lds + 6144;
  int tid = threadIdx.x, lane = tid & 63, wv = tid >> 6;
  int r = lane & 15, o = lane >> 4;
  const short* pa_h = Ah + (size_t)(m0 + wv * 16 + r) * K + o * 8;
  const short* pa_l = Al + (size_t)(m0 + wv * 16 + r) * K + o * 8;
  const short* pb_h = Bh + (size_t)(n0 + wv * 16 + r) * K + o * 8;
  const short* pb_l = Bl + (size_t)(n0 + wv * 16 + r) * K + o * 8;
  int wm = (wv >> 1) * 32, wn = (wv & 1) * 32;
  int ab = wm >> 4, bb = wn >> 4;
  floatx4 acc[2][2] = {};
  for (int k0 = 0; k0 < K; k0 += 32) {
    gll16(pa_h + k0, As_h + wv * 512);
    gll16(pa_l + k0, As_l + wv * 512);
    gll16(pb_h + k0, Bs_h + wv * 512);
    gll16(pb_l + k0, Bs_l + wv * 512);
    __syncthreads();
    short8 ah[2], al2[2], bh[2], bl2[2];
#pragma unroll
    for (int i = 0; i < 2; ++i) {
      ah[i] = *(const short8*)(As_h + (ab + i) * 512 + lane * 8);
      al2[i] = *(const short8*)(As_l + (ab + i) * 512 + lane * 8);
      bh[i] = *(const short8*)(Bs_h + (bb + i) * 512 + lane * 8);
      bl2[i] = *(const short8*)(Bs_l + (bb + i) * 512 + lane * 8);
    }
#pragma unroll
    for (int i = 0; i < 2; ++i)
#pragma unroll
      for (int j = 0; j < 2; ++j) {
        acc[i][j] = __builtin_amdgcn_mfma_f32_16x16x32_bf16(ah[i], bh[j], acc[i][j], 0, 0, 0);
        acc[i][j] = __builtin_amdgcn_mfma_f32_16x16x32_bf16(ah[i], bl2[j], acc[i][j], 0, 0, 0);
        acc[i][j] = __builtin_amdgcn_mfma_f32_16x16x32_bf16(al2[i], bh[j], acc[i][j], 0, 0, 0);
      }
    __syncthreads();
  }
  int x = lane & 15, g = lane >> 4;
#pragma unroll
  for (int i = 0; i < 2; ++i) {
#pragma unroll
    for (int j = 0; j < 2; ++j) {
      int col = n0 + wn + 16 * j + x;
      int row0 = m0 + wm + 16 * i + 4 * g;
      floatx4 f = acc[i][j];
#pragma unroll
      for (int rr = 0; rr < 4; ++rr) {
        float v = f[rr];
        if (act == 1) {
          float hh = (v >= 0.f) ? v : 0.5f * v;
          v = hh * hh;
        }
        if (colscale) v *= colscale[col];
        size_t idx = (size_t)(row0 + rr) * N + col;
        if (base) v += base[idx];
        C[idx] = v;
      }
    }
  }
}

__global__ __launch_bounds__(256) void gemm64_p(
    const short* __restrict__ Ah, const short* __restrict__ Al,
    const short* __restrict__ Bh, const short* __restrict__ Bl,
    float* __restrict__ C, const float* __restrict__ base,
    const float* __restrict__ colscale, int N, int K, int act) {
  __shared__ short lds[8192];
  int bx = blockIdx.x, by = blockIdx.y;
  xcd_swizzle(bx, by, gridDim.x, gridDim.y);
  gemm64_body(Ah, Al, Bh, Bl, C, base, colscale, N, K, act, bx * 64, by * 64,
              lds);
}

// Fused K+V projection: grid (M/64, 8); by<4 -> K panel, by>=4 -> V panel.
__global__ __launch_bounds__(256) void gemm64_kv(
    const short* __restrict__ Ah, const short* __restrict__ Al,
    const short* __restrict__ Kh, const short* __restrict__ Kl,
    const short* __restrict__ Vh, const short* __restrict__ Vl,
    float* __restrict__ Ck, float* __restrict__ Cv,
    const float* __restrict__ vemb, int K) {
  __shared__ short lds[8192];
  int bx = blockIdx.x, by = blockIdx.y;
  xcd_swizzle(bx, by, gridDim.x, gridDim.y);
  int sel = by >> 2, byl = by & 3;
  gemm64_body(Ah, Al, sel ? Vh : Kh, sel ? Vl : Kl, sel ? Cv : Ck,
              sel ? vemb : nullptr, nullptr, KVDc, K, 0, bx * 64, byl * 64,
              lds);
}

// ---------------------------------------------------------------------------
// QK head-RMS + RoPE (+q_gain). Block per token.
// ---------------------------------------------------------------------------
__global__ __launch_bounds__(256) void qkrope_kernel(
    float* __restrict__ q, float* __restrict__ k,
    const float* __restrict__ q_gain) {
  int bt = blockIdx.x;
  int t = bt % Tc;
  int tid = threadIdx.x;
  int lane = tid & 63, wv = tid >> 6;
  int fi = lane & 31;
  float inv = expf(-(float)(2 * fi) * (9.210340372f / 64.f));
  float ang = (float)t * inv;
  float cv = cosf(ang);
  float sv = sinf(ang);

#pragma unroll
  for (int hh = 0; hh < 4; ++hh) {
    int h = wv + hh * 4;
    float* qp = q + (size_t)bt * Dc + h * 64;
    float val = qp[lane];
    float ss = wave_sum(val * val);
    float rn = rsqrtf(ss / 64.f + 1e-6f);
    val *= rn;
    float partner = __shfl(val, lane ^ 32);
    float out = (lane < 32) ? (val * cv + partner * sv) : (val * cv - partner * sv);
    out *= q_gain[h];
    qp[lane] = out;
  }
  {
    int h = wv;
    float* kp = k + (size_t)bt * KVDc + h * 64;
    float val = kp[lane];
    float ss = wave_sum(val * val);
    float rn = rsqrtf(ss / 64.f + 1e-6f);
    val *= rn;
    float partner = __shfl(val, lane ^ 32);
    float out = (lane < 32) ? (val * cv + partner * sv) : (val * cv - partner * sv);
    kp[lane] = out;
  }
}

// ---------------------------------------------------------------------------
// MFMA causal GQA flash attention + v-direction-removal epilogue.
// Output written as bf16 hi/lo planes (consumed by Wo plane-GEMM).
// ---------------------------------------------------------------------------
__global__ __launch_bounds__(256) void attn_mfma(
    const float* __restrict__ qg_, const float* __restrict__ kg_,
    const float* __restrict__ vg_, short* __restrict__ yh_,
    short* __restrict__ yl_) {
  __shared__ short smem[32768];  // 64 KiB
  short* Khi  = smem;
  short* Klo  = smem + 4096;
  short* Vthi = smem + 8192;
  short* Vtlo = smem + 12288;

  int qt = blockIdx.x;
  int bh = blockIdx.y;
  int b = bh >> 2, hkv = bh & 3;
  int tid = threadIdx.x;
  int lane = tid & 63, wv = tid >> 6;
  int x = lane & 15, g = lane >> 4;
  int h = hkv * 4 + wv;
  int qbase = qt * 32;

  short* PAhi = smem + 16384 + wv * 2048;
  short* PAlo = smem + 24576 + wv * 2048;

  short8 qh[2][2], qlo[2][2];
#pragma unroll
  for (int j = 0; j < 2; ++j)
#pragma unroll
    for (int ks = 0; ks < 2; ++ks) {
      int qrow = qbase + 16 * j + x;
      const float* qp =
          qg_ + ((size_t)(b * Tc + qrow)) * Dc + h * 64 + ks * 32 + g * 8;
      float4 f0 = *(const float4*)qp;
      float4 f1 = *(const float4*)(qp + 4);
      float fv[8] = {f0.x, f0.y, f0.z, f0.w, f1.x, f1.y, f1.z, f1.w};
#pragma unroll
      for (int e = 0; e < 8; ++e) {
        short hb = f2bf(fv[e]);
        qh[j][ks][e] = hb;
        qlo[j][ks][e] = f2bf(fv[e] - bf2f(hb));
      }
    }

  floatx4 o[2][4] = {};
  float m_run[2] = {NEG_BIG, NEG_BIG};
  float l_run[2] = {0.f, 0.f};

  int nkt = (qbase >> 6) + 1;
  for (int kt = 0; kt < nkt; ++kt) {
    {
      int r = tid >> 2, kgl = tid & 3;
#pragma unroll
      for (int half = 0; half < 2; ++half) {
        int d0 = kgl * 8 + half * 32;
        const float* src =
            kg_ + ((size_t)(b * Tc + kt * 64 + r)) * KVDc + hkv * 64 + d0;
        float4 f0 = *(const float4*)src;
        float4 f1 = *(const float4*)(src + 4);
        float fv[8] = {f0.x, f0.y, f0.z, f0.w, f1.x, f1.y, f1.z, f1.w};
        short8 h8, l8;
#pragma unroll
        for (int e = 0; e < 8; ++e) {
          short hb = f2bf(fv[e]);
          h8[e] = hb;
          l8[e] = f2bf(fv[e] - bf2f(hb));
        }
        int off = half * 2048 + (r >> 4) * 512 + ((r & 15) + kgl * 16) * 8;
        *(short8*)(Khi + off) = h8;
        *(short8*)(Klo + off) = l8;
      }
    }
    {
      int d = 16 * wv + x;
#pragma unroll
      for (int ks = 0; ks < 2; ++ks) {
        float fv[8];
#pragma unroll
        for (int e = 0; e < 8; ++e) {
          int kk = ks * 32 + g * 8 + e;
          fv[e] = vg_[((size_t)(b * Tc + kt * 64 + kk)) * KVDc + hkv * 64 + d];
        }
        short8 hi8, lo8;
#pragma unroll
        for (int e = 0; e < 8; ++e) {
          short hb = f2bf(fv[e]);
          hi8[e] = hb;
          lo8[e] = f2bf(fv[e] - bf2f(hb));
        }
        int off = ks * 2048 + wv * 512 + (x + g * 16) * 8;
        *(short8*)(Vthi + off) = hi8;
        *(short8*)(Vtlo + off) = lo8;
      }
    }
    __syncthreads();

    floatx4 st[4][2] = {};
#pragma unroll
    for (int ks = 0; ks < 2; ++ks) {
#pragma unroll
      for (int i = 0; i < 4; ++i) {
        short8 ka_h = *(const short8*)(Khi + ks * 2048 + i * 512 + lane * 8);
        short8 ka_l = *(const short8*)(Klo + ks * 2048 + i * 512 + lane * 8);
#pragma unroll
        for (int j = 0; j < 2; ++j) {
          st[i][j] = __builtin_amdgcn_mfma_f32_16x16x32_bf16(ka_h, qh[j][ks], st[i][j], 0, 0, 0);
          st[i][j] = __builtin_amdgcn_mfma_f32_16x16x32_bf16(ka_h, qlo[j][ks], st[i][j], 0, 0, 0);
          st[i][j] = __builtin_amdgcn_mfma_f32_16x16x32_bf16(ka_l, qh[j][ks], st[i][j], 0, 0, 0);
        }
      }
    }

    float al[2];
#pragma unroll
    for (int j = 0; j < 2; ++j) {
      int qrow = qbase + 16 * j + x;
      float mx = NEG_BIG;
#pragma unroll
      for (int i = 0; i < 4; ++i) {
#pragma unroll
        for (int r = 0; r < 4; ++r) {
          int krow = kt * 64 + 16 * i + 4 * g + r;
          float s = st[i][j][r] * 0.125f;
          if (krow > qrow) s = NEG_BIG;
          st[i][j][r] = s;
          mx = fmaxf(mx, s);
        }
      }
      mx = fmaxf(mx, __shfl_xor(mx, 16));
      mx = fmaxf(mx, __shfl_xor(mx, 32));
      float m_new = fmaxf(m_run[j], mx);
      al[j] = __expf(m_run[j] - m_new);
      float ts = 0.f;
#pragma unroll
      for (int i = 0; i < 4; ++i) {
#pragma unroll
        for (int r = 0; r < 4; ++r) {
          float p = __expf(st[i][j][r] - m_new);
          st[i][j][r] = p;
          ts += p;
        }
      }
      ts += __shfl_xor(ts, 16);
      ts += __shfl_xor(ts, 32);
      l_run[j] = l_run[j] * al[j] + ts;
      m_run[j] = m_new;
    }

#pragma unroll
    for (int j = 0; j < 2; ++j) {
#pragma unroll
      for (int i = 0; i < 4; ++i) {
        short4v h4, l4;
#pragma unroll
        for (int r = 0; r < 4; ++r) {
          float p = st[i][j][r];
          short hb = f2bf(p);
          h4[r] = hb;
          l4[r] = f2bf(p - bf2f(hb));
        }
        int offp = (i >> 1) * 1024 + j * 512 +
                   (x + (2 * (i & 1) + (g >> 1)) * 16) * 8 + 4 * (g & 1);
        *(short4v*)(PAhi + offp) = h4;
        *(short4v*)(PAlo + offp) = l4;
      }
    }

#pragma unroll
    for (int iO = 0; iO < 2; ++iO) {
#pragma unroll
      for (int r = 0; r < 4; ++r) {
        float a = __shfl(al[iO], 4 * g + r);
#pragma unroll
        for (int jd = 0; jd < 4; ++jd) o[iO][jd][r] *= a;
      }
    }
    __syncthreads();

#pragma unroll
    for (int ks = 0; ks < 2; ++ks) {
      short8 pa_h[2], pa_l[2];
#pragma unroll
      for (int iO = 0; iO < 2; ++iO) {
        pa_h[iO] = *(const short8*)(PAhi + ks * 1024 + iO * 512 + lane * 8);
        pa_l[iO] = *(const short8*)(PAlo + ks * 1024 + iO * 512 + lane * 8);
      }
#pragma unroll
      for (int jd = 0; jd < 4; ++jd) {
        short8 vb_h = *(const short8*)(Vthi + ks * 2048 + jd * 512 + lane * 8);
        short8 vb_l = *(const short8*)(Vtlo + ks * 2048 + jd * 512 + lane * 8);
#pragma unroll
        for (int iO = 0; iO < 2; ++iO) {
          o[iO][jd] = __builtin_amdgcn_mfma_f32_16x16x32_bf16(pa_h[iO], vb_h, o[iO][jd], 0, 0, 0);
          o[iO][jd] = __builtin_amdgcn_mfma_f32_16x16x32_bf16(pa_h[iO], vb_l, o[iO][jd], 0, 0, 0);
          o[iO][jd] = __builtin_amdgcn_mfma_f32_16x16x32_bf16(pa_l[iO], vb_h, o[iO][jd], 0, 0, 0);
        }
      }
    }
    __syncthreads();
  }

#pragma unroll
  for (int iO = 0; iO < 2; ++iO) {
#pragma unroll
    for (int r = 0; r < 4; ++r) {
      float lr = __shfl(l_run[iO], 4 * g + r);
      float rcp = 1.f / lr;
      int qrow = qbase + 16 * iO + 4 * g + r;
      const float* vr = vg_ + ((size_t)(b * Tc + qrow)) * KVDc + hkv * 64;
      float vv[4], oo[4];
      float pn = 0.f, pd = 0.f;
#pragma unroll
      for (int jd = 0; jd < 4; ++jd) {
        vv[jd] = vr[16 * jd + x];
        oo[jd] = o[iO][jd][r] * rcp;
        pn += vv[jd] * vv[jd];
        pd += oo[jd] * vv[jd];
      }
#pragma unroll
      for (int off = 1; off <= 8; off <<= 1) {
        pn += __shfl_xor(pn, off);
        pd += __shfl_xor(pd, off);
      }
      float nrm = sqrtf(pn);
      float mxv = fmaxf(nrm, 1e-12f);
      float si = 1.f / mxv;
      float co = pd * si * si;
      size_t ybase = ((size_t)(b * Tc + qrow)) * Dc + h * 64;
#pragma unroll
      for (int jd = 0; jd < 4; ++jd) {
        float val = oo[jd] - co * vv[jd];
        short hb = f2bf(val);
        yh_[ybase + 16 * jd + x] = hb;
        yl_[ybase + 16 * jd + x] = f2bf(val - bf2f(hb));
      }
    }
  }
}

// ---------------------------------------------------------------------------
extern "C" void kernel_launch(void* const* d_in, const int* in_sizes, int n_in,
                              void* d_out, int out_size, void* d_ws,
                              size_t ws_size, hipStream_t stream) {
  const int* ids          = (const int*)d_in[0];
  const float* embed_w    = (const float*)d_in[1];
  const float* big_w      = (const float*)d_in[2];
  const float* big_proj   = (const float*)d_in[3];
  const float* big_scale  = (const float*)d_in[4];
  const float* smear_gate = (const float*)d_in[5];
  const float* ve_w       = (const float*)d_in[6];
  const float* ve_proj    = (const float*)d_in[7];
  const float* ve_scale   = (const float*)d_in[8];
  const float* Wq         = (const float*)d_in[9];
  const float* Wk         = (const float*)d_in[10];
  const float* Wv         = (const float*)d_in[11];
  const float* Wo         = (const float*)d_in[12];
  const float* q_gain     = (const float*)d_in[13];
  const float* attn_scale = (const float*)d_in[14];
  const float* mlp_scale  = (const float*)d_in[15];
  const float* resid_mix  = (const float*)d_in[16];
  const float* Wfc        = (const float*)d_in[17];
  const float* Wp         = (const float*)d_in[18];
  const float* head_w     = (const float*)d_in[19];
  float* out = (float*)d_out;

  // ---- workspace layout ----
  char* p = (char*)d_ws;
  float* x     = (float*)p; p += SZ_X * 4;
  float* x0    = (float*)p; p += SZ_X * 4;
  float* x_in  = (float*)p; p += SZ_X * 4;
  float* qb    = (float*)p; p += SZ_X * 4;
  float* kb    = (float*)p; p += SZ_KV * 4;
  float* vb    = (float*)p; p += SZ_KV * 4;
  float* vemb  = (float*)p; p += SZ_KV * 4;
  float* raw_x = (float*)p; p += SZ_X * 4;
  short* xnh = (short*)p; p += SZ_X * 2;
  short* xnl = (short*)p; p += SZ_X * 2;
  short* yh  = (short*)p; p += SZ_X * 2;
  short* yl  = (short*)p; p += SZ_X * 2;
  short* hh  = (short*)p; p += SZ_H * 2;
  short* hl  = (short*)p; p += SZ_H * 2;
  short* wqh = (short*)p; p += W_Q * 2;
  short* wql = (short*)p; p += W_Q * 2;
  short* wkh = (short*)p; p += W_KV * 2;
  short* wkl = (short*)p; p += W_KV * 2;
  short* wvh = (short*)p; p += W_KV * 2;
  short* wvl = (short*)p; p += W_KV * 2;
  short* woh = (short*)p; p += W_Q * 2;
  short* wol = (short*)p; p += W_Q * 2;
  short* wfh = (short*)p; p += W_FC * 2;
  short* wfl = (short*)p; p += W_FC * 2;
  short* wph = (short*)p; p += W_FC * 2;
  short* wpl = (short*)p; p += W_FC * 2;
  short* hwh = (short*)p; p += W_HD * 2;
  short* hwl = (short*)p; p += W_HD * 2;

  // ---- weight conversion (memory-bound, ~175 us total) ----
  auto wc = [&](const float* s, short* h, short* l2, long n) {
    long n8 = n / 8;
    int blocks = (int)((n8 + 255) / 256);
    wcvt_kernel<<<blocks, 256, 0, stream>>>(s, h, l2, n8);
  };
  wc(Wq, wqh, wql, W_Q);
  wc(Wk, wkh, wkl, W_KV);
  wc(Wv, wvh, wvl, W_KV);
  wc(Wo, woh, wol, W_Q);
  wc(Wfc, wfh, wfl, W_FC);
  wc(Wp, wph, wpl, W_FC);
  wc(head_w, hwh, hwl, W_HD);

  embed_kernel<<<NTOK, 256, 0, stream>>>(ids, embed_w, big_w, big_proj,
                                         big_scale, ve_w, ve_proj, ve_scale,
                                         raw_x, vemb);
  smear_kernel<<<(int)(SZ_X / 256), 256, 0, stream>>>(raw_x, smear_gate, x, x0);

  for (int l = 0; l < Lc; ++l) {
    const float* mix = resid_mix + (size_t)l * 2 * Dc;
    prelayer_kernel<<<NTOK, 256, 0, stream>>>(x, x0, mix, x_in, xnh, xnl);
    // q projection
    gemm64_p<<<dim3(NTOK / 64, Dc / 64), 256, 0, stream>>>(
        xnh, xnl, wqh + (size_t)l * Dc * Dc, wql + (size_t)l * Dc * Dc, qb,
        nullptr, nullptr, Dc, Dc, 0);
    // fused k,v projections
    gemm64_kv<<<dim3(NTOK / 64, 8), 256, 0, stream>>>(
        xnh, xnl, wkh + (size_t)l * KVDc * Dc, wkl + (size_t)l * KVDc * Dc,
        wvh + (size_t)l * KVDc * Dc, wvl + (size_t)l * KVDc * Dc, kb, vb, vemb,
        Dc);
    qkrope_kernel<<<NTOK, 256, 0, stream>>>(qb, kb, q_gain + (size_t)l * Hc);
    attn_mfma<<<dim3(Tc / 32, Bc * HKVc), 256, 0, stream>>>(qb, kb, vb, yh, yl);
    // out proj + residual: x = x_in + attn_scale * (y @ Wo.T)
    gemm64_p<<<dim3(NTOK / 64, Dc / 64), 256, 0, stream>>>(
        yh, yl, woh + (size_t)l * Dc * Dc, wol + (size_t)l * Dc * Dc, x, x_in,
        attn_scale + (size_t)l * Dc, Dc, Dc, 0);
    // MLP
    rms_split_kernel<<<NTOK, 256, 0, stream>>>(x, xnh, xnl);
    gemm128_p<<<dim3(NTOK / 128, MLPc / 128), 256, 0, stream>>>(
        xnh, xnl, wfh + (size_t)l * MLPc * Dc, wfl + (size_t)l * MLPc * Dc,
        nullptr, hh, hl, nullptr, nullptr, NTOK, MLPc, Dc, 1);
    gemm64_p<<<dim3(NTOK / 64, Dc / 64), 256, 0, stream>>>(
        hh, hl, wph + (size_t)l * Dc * MLPc, wpl + (size_t)l * Dc * MLPc, x, x,
        mlp_scale + (size_t)l * Dc, Dc, MLPc, 0);
  }

  rms_split_kernel<<<NTOK, 256, 0, stream>>>(x, xnh, xnl);
  gemm128_p<<<dim3(NTOK / 128, (Vc + 127) / 128), 256, 0, stream>>>(
      xnh, xnl, hwh, hwl, out, nullptr, nullptr, nullptr, nullptr, NTOK, Vc,
      Dc, 0);
}